// Round 1
// 160.780 us; speedup vs baseline: 1.0708x; 1.0708x over previous
//
#include <hip/hip_runtime.h>

typedef unsigned short u16;
typedef unsigned int u32;

#define B_ 2
#define L_ 4096
#define D_ 512
#define H_ 8
#define E_ 64
#define M_ (B_*L_)        // 8192 rows
#define TD (3*D_)         // 1536
#define NCH (L_/64)       // 64 chunks of 64 per sequence
#define BH (B_*H_)        // 16

typedef short bf16x8 __attribute__((ext_vector_type(8)));
typedef float f32x4 __attribute__((ext_vector_type(4)));

__device__ __forceinline__ float bf2f(u16 u){ return __uint_as_float(((u32)u)<<16); }
__device__ __forceinline__ u16 f2bf(float f){
  u32 u = __float_as_uint(f);
  u32 r = u + 0x7FFFu + ((u>>16)&1u);   // RNE; inputs finite
  return (u16)(r>>16);
}
__device__ __forceinline__ float elu1(float v){ return v>0.f ? v+1.f : __expf(v); }

__device__ __forceinline__ void async_ld16(const u16* g, u16* l){
  __builtin_amdgcn_global_load_lds(
      (const __attribute__((address_space(1))) void*)g,
      (__attribute__((address_space(3))) void*)l, 16, 0, 0);
}

// ---------------- K1: decay logits + x->bf16 + weight conversions ----------------
// blocks 0..2047: 4 rows each (decay logits + xb);  blocks 2048..3071: qw/ow -> bf16
__global__ __launch_bounds__(256) void decay_conv_kernel(const float* __restrict__ x,
    const float* __restrict__ dw, const float* __restrict__ db,
    const float* __restrict__ qw, const float* __restrict__ ow,
    float* __restrict__ ll, u16* __restrict__ xb,
    u16* __restrict__ qwb, u16* __restrict__ owb)
{
  int blk = blockIdx.x;
  if (blk < 2048){
    int wv = threadIdx.x>>6, lane = threadIdx.x&63;
    int m = blk*4 + wv;
    float xr[8];
    #pragma unroll
    for (int i=0;i<8;i++) xr[i] = x[(size_t)m*D_ + lane + 64*i];
    #pragma unroll
    for (int i=0;i<8;i++) xb[(size_t)m*D_ + lane + 64*i] = f2bf(xr[i]);
    int b = m >> 12, l = m & (L_-1);
    for (int h=0; h<H_; h++){
      float acc = 0.f;
      #pragma unroll
      for (int i=0;i<8;i++) acc += xr[i]*dw[h*D_ + lane + 64*i];
      #pragma unroll
      for (int off=32; off>0; off>>=1) acc += __shfl_xor(acc, off);
      if (lane == h){
        float z = acc + db[h];
        float lam = 0.9f + 0.1f/(1.f + __expf(-z));
        ll[((b*H_+h)*L_) + l] = logf(lam);
      }
    }
  } else {
    int gid = (blk-2048)*256 + threadIdx.x;   // 262144 float4 groups
    const float* src; u16* dst; int off;
    if (gid < 196608){ src = qw; dst = qwb; off = gid; }
    else { src = ow; dst = owb; off = gid - 196608; }
    float4 v = ((const float4*)src)[off];
    ushort4 o; o.x=f2bf(v.x); o.y=f2bf(v.y); o.z=f2bf(v.z); o.w=f2bf(v.w);
    ((ushort4*)dst)[off] = o;
  }
}

// ---------------- K2: inclusive scan over L (shfl-based), clip to [-50,50] ----------------
__global__ __launch_bounds__(256) void scan_kernel(const float* __restrict__ ll,
    float* __restrict__ cb)
{
  int bh = blockIdx.x, t = threadIdx.x;
  int lane = t & 63, wv = t >> 6;
  const float* p = ll + (size_t)bh*L_ + t*16;
  float s[16];
  #pragma unroll
  for (int q=0;q<4;q++){
    float4 v = *(const float4*)(p + q*4);
    s[q*4+0]=v.x; s[q*4+1]=v.y; s[q*4+2]=v.z; s[q*4+3]=v.w;
  }
  #pragma unroll
  for (int i=1;i<16;i++) s[i] += s[i-1];
  float tot = s[15];
  float ws = tot;
  #pragma unroll
  for (int off=1; off<64; off<<=1){
    float tmp = __shfl_up(ws, off);
    if (lane >= off) ws += tmp;
  }
  __shared__ float wsum[4];
  if (lane == 63) wsum[wv] = ws;
  __syncthreads();
  float base = 0.f;
  #pragma unroll
  for (int w2=0; w2<3; w2++) if (w2 < wv) base += wsum[w2];
  float ex = base + ws - tot;
  float* c = cb + (size_t)bh*L_ + t*16;
  #pragma unroll
  for (int i=0;i<16;i++) c[i] = fminf(50.f, fmaxf(-50.f, ex + s[i]));
}

// ---------------- MFMA GEMM: C[m][n] = sum_k A[m][k]*W[n][k] + bias[n] ----------------
template<bool OB>
__global__ __launch_bounds__(256) void gemm_mfma(const u16* __restrict__ A,
    const u16* __restrict__ W, const float* __restrict__ bias,
    void* __restrict__ Cv, int M, int N, int K)
{
  __shared__ u16 As[128*32];
  __shared__ u16 Bs[128*32];
  int n0 = blockIdx.x*128, m0 = blockIdx.y*128;
  int t = threadIdx.x, wave = t>>6, lane = t&63;
  int wm = (wave>>1)*64, wn = (wave&1)*64;
  f32x4 acc[4][4] = {};
  int srow = wave*32 + (lane>>2);
  int scol = (lane&3)*8;
  const u16* gA = A + (size_t)(m0+srow)*K + scol;
  const u16* gB = W + (size_t)(n0+srow)*K + scol;
  u16* lA = As + wave*1024;
  u16* lB = Bs + wave*1024;
  int q8 = (lane>>4)*8, r16 = lane&15;
  for (int k0=0; k0<K; k0+=32){
    async_ld16(gA + k0,                lA);
    async_ld16(gA + k0 + 16*(size_t)K, lA + 512);
    async_ld16(gB + k0,                lB);
    async_ld16(gB + k0 + 16*(size_t)K, lB + 512);
    __syncthreads();
    bf16x8 af[4], bfr[4];
    #pragma unroll
    for (int i=0;i<4;i++) af[i]  = *(const bf16x8*)&As[(wm + i*16 + r16)*32 + q8];
    #pragma unroll
    for (int j=0;j<4;j++) bfr[j] = *(const bf16x8*)&Bs[(wn + j*16 + r16)*32 + q8];
    #pragma unroll
    for (int i=0;i<4;i++)
      #pragma unroll
      for (int j=0;j<4;j++)
        acc[i][j] = __builtin_amdgcn_mfma_f32_16x16x32_bf16(af[i], bfr[j], acc[i][j], 0,0,0);
    __syncthreads();
  }
  #pragma unroll
  for (int i=0;i<4;i++){
    int row = m0 + wm + i*16 + (lane>>4)*4;
    #pragma unroll
    for (int j=0;j<4;j++){
      int col = n0 + wn + j*16 + r16;
      float bv = bias[col];
      #pragma unroll
      for (int r=0;r<4;r++){
        float val = acc[i][j][r] + bv;
        if (OB) ((u16*)Cv)[(size_t)(row+r)*N + col] = f2bf(val);
        else    ((float*)Cv)[(size_t)(row+r)*N + col] = val;
      }
    }
  }
}

// ---------------- K4: fused transform + transpose + chunk S^T MFMA ----------------
// Ktl/Vtl padded to stride 40 u16 (80 B): ds_write conflicts 32-way -> 8-way.
// Ks/Vs padded to stride 72 u16 (144 B): keeps 16B-aligned uint4 stores.
__global__ __launch_bounds__(256) void transform_sums_kernel(const u16* __restrict__ qkvb,
    const float* __restrict__ cb, u16* __restrict__ qc, u16* __restrict__ kc,
    u16* __restrict__ vtc, u16* __restrict__ Stc, float* __restrict__ ksc)
{
  int bid = blockIdx.x;
  int bh = bid >> 6, ch = bid & 63;
  int b = bh >> 3, h = bh & 7;
  __shared__ u16 Ks[64*72];
  __shared__ u16 Vs[64*72];
  __shared__ u16 Ktl[128*40];
  __shared__ u16 Vtl[128*40];
  __shared__ float ksr[256];
  int t = threadIdx.x;
  size_t mbase = (size_t)b*L_ + ch*64;
  #pragma unroll
  for (int i=0;i<2;i++){
    int idx = t + 256*i;
    int l = idx>>3, e0 = (idx&7)*8;
    int kh = e0>>5, ej = e0&31;
    float c = cb[(size_t)bh*L_ + ch*64 + l];
    float eqc = __expf(c)*0.125f, ekc = __expf(-c);
    const u16* src = qkvb + (mbase+l)*TD + h*64 + e0;
    union { uint4 v; u16 s[8]; } in, o;
    // q
    in.v = *(const uint4*)src;
    #pragma unroll
    for (int j=0;j<8;j++) o.s[j] = f2bf(elu1(bf2f(in.s[j]))*eqc);
    *(uint4*)(qc + ((size_t)bid*2 + kh)*2048 + l*32 + ej) = o.v;
    // k
    in.v = *(const uint4*)(src + D_);
    #pragma unroll
    for (int j=0;j<8;j++) o.s[j] = f2bf(elu1(bf2f(in.s[j]))*ekc);
    *(uint4*)(kc + ((size_t)bid*2 + kh)*2048 + l*32 + ej) = o.v;
    *(uint4*)&Ks[l*72+e0] = o.v;
    // v
    *(uint4*)&Vs[l*72+e0] = *(const uint4*)(src + 2*D_);
  }
  __syncthreads();
  // transpose: thread (jq,e) -> K^T/V^T rows e, j in [jq*16, jq*16+16)
  int e = t & 63, jq = t >> 6;
  {
    u16 kv[16] __attribute__((aligned(16)));
    u16 vv[16] __attribute__((aligned(16)));
    float ksum = 0.f;
    #pragma unroll
    for (int jj=0;jj<16;jj++){
      int j = jq*16+jj;
      kv[jj] = Ks[j*72 + e];
      ksum += bf2f(kv[jj]);
      vv[jj] = Vs[j*72 + e];
    }
    int kh = jq>>1, jl = (jq&1)*16;
    u16* kt = &Ktl[(kh*64 + e)*40 + jl];
    u16* vt = &Vtl[(kh*64 + e)*40 + jl];
    *(uint4*)kt     = *(const uint4*)&kv[0];
    *(uint4*)(kt+8) = *(const uint4*)&kv[8];
    *(uint4*)vt     = *(const uint4*)&vv[0];
    *(uint4*)(vt+8) = *(const uint4*)&vv[8];
    ksr[t] = ksum;
  }
  __syncthreads();
  // Vtl -> global (chunked, unpadded stride-32 layout)
  {
    int row = t>>1, c0 = (t&1)*16;
    *(uint4*)&vtc[(size_t)bid*4096 + row*32 + c0]     = *(const uint4*)&Vtl[row*40 + c0];
    *(uint4*)&vtc[(size_t)bid*4096 + row*32 + c0 + 8] = *(const uint4*)&Vtl[row*40 + c0 + 8];
  }
  // MFMA: St[f][e] = sum_j Vt[f][j] Kt[e][j]
  int w = t>>6, lane = t&63;
  int r16 = lane & 15, q8 = (lane>>4)*8;
  bf16x8 av[2];
  #pragma unroll
  for (int kh=0;kh<2;kh++)
    av[kh] = *(const bf16x8*)&Vtl[(kh*64 + w*16 + r16)*40 + q8];
  f32x4 acc[4] = {};
  #pragma unroll
  for (int et=0;et<4;et++)
    #pragma unroll
    for (int kh=0;kh<2;kh++){
      bf16x8 bv = *(const bf16x8*)&Ktl[(kh*64 + et*16 + r16)*40 + q8];
      acc[et] = __builtin_amdgcn_mfma_f32_16x16x32_bf16(av[kh], bv, acc[et], 0,0,0);
    }
  #pragma unroll
  for (int et=0;et<4;et++){
    int eh = et>>1, el = (et&1)*16 + r16;
    #pragma unroll
    for (int r=0;r<4;r++){
      int f = w*16 + (lane>>4)*4 + r;
      Stc[((size_t)bid*2 + eh)*2048 + f*32 + el] = f2bf(acc[et][r]);
    }
  }
  if (t < 64) ksc[bid*64 + t] = ksr[t] + ksr[64+t] + ksr[128+t] + ksr[192+t];
}

// ---------------- K5: exclusive prefix over chunks ----------------
// blocks 0..127: Stc scan (u32-packed bf16 pairs), unroll 8 (8 loads in flight)
// blocks 128..131: ksc scan in parallel (was a serial tail on the first 1024 threads)
__global__ __launch_bounds__(256) void chunk_prefix_kernel(u16* __restrict__ Stc,
    float* __restrict__ ksc)
{
  int blk = blockIdx.x, t = threadIdx.x;
  if (blk < 128){
    int gid = blk*256 + t;                 // 32768 threads
    int bh = gid >> 11, e2 = gid & 2047;
    u32* p = (u32*)Stc + (size_t)bh*131072 + e2;
    float r0 = 0.f, r1 = 0.f;
    #pragma unroll 8
    for (int ch=0; ch<NCH; ch++){
      u32 v = p[ch*2048];
      float lo = bf2f((u16)(v & 0xffffu));
      float hi = bf2f((u16)(v >> 16));
      p[ch*2048] = (u32)f2bf(r0) | ((u32)f2bf(r1) << 16);
      r0 += lo; r1 += hi;
    }
  } else {
    int gid2 = (blk-128)*256 + t;          // 1024 threads = BH*64
    int bh2 = gid2 >> 6, e = gid2 & 63;
    float* kp = ksc + bh2*4096 + e;
    float kr = 0.f;
    #pragma unroll 8
    for (int ch=0; ch<NCH; ch++){
      float v = kp[ch*64]; kp[ch*64] = kr; kr += v;
    }
  }
}

// ---------------- K6: chunk output via MFMA (async chunked staging) ----------------
__global__ __launch_bounds__(256) void chunk_out_kernel(const u16* __restrict__ qc,
    const u16* __restrict__ kc, const u16* __restrict__ vtc,
    const u16* __restrict__ Stc, const float* __restrict__ ksc,
    u16* __restrict__ attn)
{
  int bid = blockIdx.x;
  int bh = bid >> 6, ch = bid & 63;
  int b = bh >> 3, h = bh & 7;
  __shared__ u16 KV[16384];     // Qs | Kb_s | Vt_s | St_s, each [half][row][32]
  __shared__ u16 Ab[4096];      // [jh][l][32]
  __shared__ float kp[64], den4[256], den[64];
  int t = threadIdx.x, w = t>>6, lane = t&63;
  size_t mbase = (size_t)b*L_ + ch*64;
  const u16* srcs[4] = { qc, kc, vtc, Stc };
  {
    const u16* gbase = srcs[w] + (size_t)bid*4096 + lane*8;
    #pragma unroll
    for (int q=0;q<8;q++)
      async_ld16(gbase + q*512, KV + w*4096 + q*512);
  }
  if (t < 64) kp[t] = ksc[bid*64 + t];
  __syncthreads();   // B1
  const u16* Qs   = KV;
  const u16* Kb_s = KV + 4096;
  const u16* Vt_s = KV + 8192;
  const u16* St_s = KV + 12288;
  int r16 = lane & 15, q8 = (lane>>4)*8;
  // matmul1: A = Q~ K~^T  (strip l = w*16..w*16+15)
  bf16x8 aq[2];
  #pragma unroll
  for (int eh=0;eh<2;eh++)
    aq[eh] = *(const bf16x8*)&Qs[(eh*64 + w*16 + r16)*32 + q8];
  f32x4 accA[4] = {};
  #pragma unroll
  for (int jt=0;jt<4;jt++)
    #pragma unroll
    for (int eh=0;eh<2;eh++){
      bf16x8 bv = *(const bf16x8*)&Kb_s[(eh*64 + jt*16 + r16)*32 + q8];
      accA[jt] = __builtin_amdgcn_mfma_f32_16x16x32_bf16(aq[eh], bv, accA[jt], 0,0,0);
    }
  // den: q~ . kp part
  int l4 = t>>2, q4 = t&3;
  float dkp = 0.f;
  {
    int eh = q4>>1, el0 = (q4&1)*16;
    bf16x8 x1 = *(const bf16x8*)&Qs[(eh*64 + l4)*32 + el0];
    bf16x8 x2 = *(const bf16x8*)&Qs[(eh*64 + l4)*32 + el0 + 8];
    #pragma unroll
    for (int i=0;i<8;i++)
      dkp += bf2f((u16)x1[i])*kp[q4*16+i] + bf2f((u16)x2[i])*kp[q4*16+8+i];
  }
  // mask + write A to LDS (bf16, split layout)
  #pragma unroll
  for (int jt=0;jt<4;jt++)
    #pragma unroll
    for (int r=0;r<4;r++){
      int lr = w*16 + ((lane>>4)<<2) + r;
      int j  = jt*16 + r16;
      Ab[((jt>>1)*64 + lr)*32 + (jt&1)*16 + r16] = (j <= lr) ? f2bf(accA[jt][r]) : (u16)0;
    }
  __syncthreads();   // B2
  // den: masked row-sum of A
  float dA = 0.f;
  {
    int jh2 = q4>>1, jl0 = (q4&1)*16;
    bf16x8 y1 = *(const bf16x8*)&Ab[(jh2*64 + l4)*32 + jl0];
    bf16x8 y2 = *(const bf16x8*)&Ab[(jh2*64 + l4)*32 + jl0 + 8];
    #pragma unroll
    for (int i=0;i<8;i++) dA += bf2f((u16)y1[i]) + bf2f((u16)y2[i]);
  }
  den4[t] = dkp + dA;
  __syncthreads();   // B3
  if (t < 64) den[t] = den4[t*4] + den4[t*4+1] + den4[t*4+2] + den4[t*4+3] + 1e-6f;
  // matmul2: num = A V + Q~ S^T
  bf16x8 aA[2];
  #pragma unroll
  for (int jh=0;jh<2;jh++)
    aA[jh] = *(const bf16x8*)&Ab[(jh*64 + w*16 + r16)*32 + q8];
  f32x4 acc[4] = {};
  #pragma unroll
  for (int ft=0;ft<4;ft++){
    #pragma unroll
    for (int jh=0;jh<2;jh++){
      bf16x8 bv = *(const bf16x8*)&Vt_s[(jh*64 + ft*16 + r16)*32 + q8];
      acc[ft] = __builtin_amdgcn_mfma_f32_16x16x32_bf16(aA[jh], bv, acc[ft], 0,0,0);
    }
    #pragma unroll
    for (int eh=0;eh<2;eh++){
      bf16x8 bv = *(const bf16x8*)&St_s[(eh*64 + ft*16 + r16)*32 + q8];
      acc[ft] = __builtin_amdgcn_mfma_f32_16x16x32_bf16(aq[eh], bv, acc[ft], 0,0,0);
    }
  }
  __syncthreads();   // B4
  float inv[4];
  #pragma unroll
  for (int r=0;r<4;r++) inv[r] = 1.f / den[w*16 + ((lane>>4)<<2) + r];
  #pragma unroll
  for (int ft=0;ft<4;ft++)
    #pragma unroll
    for (int r=0;r<4;r++){
      int lr = w*16 + ((lane>>4)<<2) + r;
      attn[(mbase + lr)*D_ + h*64 + ft*16 + r16] = f2bf(acc[ft][r]*inv[r]);
    }
}

// ---------------- K7: out-projection GEMM fused with RMSNorm epilogue ----------------
// BM=32, BN=512 (full row band per block) so the row-wise norm closes in-kernel.
// grid = M/32 = 256 blocks, 256 threads (4 waves, each owns a 128-col band).
__global__ __launch_bounds__(256) void gemm_rms_kernel(const u16* __restrict__ A,
    const u16* __restrict__ W, const float* __restrict__ bias,
    const float* __restrict__ gnorm, float* __restrict__ out)
{
  __shared__ u16 As[32*32];
  __shared__ u16 Bs[512*32];
  __shared__ float ssq_l[4][32];
  __shared__ float rinv_l[32];
  int m0 = blockIdx.x*32;
  int t = threadIdx.x, wave = t>>6, lane = t&63;
  int wn = wave*128;
  int r16 = lane&15, q8 = (lane>>4)*8;
  f32x4 acc[2][8] = {};
  int scol = (t&3)*8;
  const u16* gB = W + (size_t)(t>>2)*512 + scol;               // rows (t>>2) + it*64
  const u16* gA = A + (size_t)(m0 + (t>>2))*512 + scol;        // valid for t<128
  u16* lB = Bs + wave*512;
  u16* lA = As + wave*512;                                     // waves 0,1 only
  for (int k0=0; k0<512; k0+=32){
    if (wave < 2) async_ld16(gA + k0, lA);
    #pragma unroll
    for (int it=0; it<8; it++)
      async_ld16(gB + k0 + it*32768, lB + it*2048);
    __syncthreads();
    bf16x8 af[2];
    af[0] = *(const bf16x8*)&As[r16*32 + q8];
    af[1] = *(const bf16x8*)&As[(16 + r16)*32 + q8];
    #pragma unroll
    for (int j=0;j<8;j++){
      bf16x8 bv = *(const bf16x8*)&Bs[(wn + j*16 + r16)*32 + q8];
      acc[0][j] = __builtin_amdgcn_mfma_f32_16x16x32_bf16(af[0], bv, acc[0][j], 0,0,0);
      acc[1][j] = __builtin_amdgcn_mfma_f32_16x16x32_bf16(af[1], bv, acc[1][j], 0,0,0);
    }
    __syncthreads();
  }
  // epilogue: bias, row sum-of-squares (across 4 waves), rsqrt, scale, fp32 store
  int g = lane>>4;
  float bv8[8], gv8[8];
  #pragma unroll
  for (int j=0;j<8;j++){ int col = wn + j*16 + r16; bv8[j] = bias[col]; gv8[j] = gnorm[col]; }
  float ssq[2][4] = {};
  #pragma unroll
  for (int i=0;i<2;i++)
    #pragma unroll
    for (int j=0;j<8;j++)
      #pragma unroll
      for (int r=0;r<4;r++){
        float v = acc[i][j][r] + bv8[j];
        acc[i][j][r] = v;
        ssq[i][r] += v*v;
      }
  #pragma unroll
  for (int off=1; off<16; off<<=1)
    #pragma unroll
    for (int i=0;i<2;i++)
      #pragma unroll
      for (int r=0;r<4;r++)
        ssq[i][r] += __shfl_xor(ssq[i][r], off);
  if (r16 == 0){
    #pragma unroll
    for (int i=0;i<2;i++)
      #pragma unroll
      for (int r=0;r<4;r++)
        ssq_l[wave][i*16 + g*4 + r] = ssq[i][r];
  }
  __syncthreads();
  if (t < 32)
    rinv_l[t] = rsqrtf((ssq_l[0][t]+ssq_l[1][t]+ssq_l[2][t]+ssq_l[3][t])*(1.f/512.f) + 1e-8f);
  __syncthreads();
  #pragma unroll
  for (int i=0;i<2;i++)
    #pragma unroll
    for (int r=0;r<4;r++){
      int row = m0 + i*16 + g*4 + r;
      float ri = rinv_l[i*16 + g*4 + r];
      #pragma unroll
      for (int j=0;j<8;j++)
        out[(size_t)row*512 + wn + j*16 + r16] = acc[i][j][r]*ri*gv8[j];
    }
}

extern "C" void kernel_launch(void* const* d_in, const int* in_sizes, int n_in,
                              void* d_out, int out_size, void* d_ws, size_t ws_size,
                              hipStream_t stream)
{
  const float* x     = (const float*)d_in[0];
  const float* w_qkv = (const float*)d_in[1];
  const float* b_qkv = (const float*)d_in[2];
  const float* w_out = (const float*)d_in[3];
  const float* b_out = (const float*)d_in[4];
  const float* w_dec = (const float*)d_in[5];
  const float* b_dec = (const float*)d_in[6];
  const float* gnorm = (const float*)d_in[7];
  float* out = (float*)d_out;

  char* ws = (char*)d_ws;
  u16*   qkvb = (u16*)(ws);                    // 25,165,824  [M][1536] bf16
  u16*   qc   = (u16*)(ws + 25165824);         //  8,388,608  chunked [bid][eh][l][32]
  u16*   kc   = (u16*)(ws + 33554432);         //  8,388,608  chunked [bid][eh][j][32]
  u16*   vtc  = (u16*)(ws + 41943040);         //  8,388,608  chunked [bid][jh][f][32]
  u16*   Stc  = (u16*)(ws + 50331648);         //  8,388,608  chunked [bid][eh][f][32]
  float* ksc  = (float*)(ws + 58720256);       //    262,144
  float* ll   = (float*)(ws + 58982400);       //    262,144
  float* cb   = (float*)(ws + 59244544);       //    262,144
  u16*   xb   = (u16*)(ws + 59506688);         //  8,388,608  (attn reuses after gemm_qkv)
  u16*   qwb  = (u16*)(ws + 67895296);         //  1,572,864
  u16*   owb  = (u16*)(ws + 69468160);         //    524,288  total 69,992,448
  u16*   attn = xb;

  decay_conv_kernel<<<dim3(3072), dim3(256), 0, stream>>>(x, w_dec, b_dec, w_qkv, w_out,
                                                          ll, xb, qwb, owb);
  scan_kernel<<<dim3(BH), dim3(256), 0, stream>>>(ll, cb);
  gemm_mfma<true><<<dim3(TD/128, M_/128), dim3(256), 0, stream>>>(xb, qwb, b_qkv, qkvb, M_, TD, D_);
  transform_sums_kernel<<<dim3(BH*NCH), dim3(256), 0, stream>>>(qkvb, cb, qc, kc, vtc, Stc, ksc);
  chunk_prefix_kernel<<<dim3(132), dim3(256), 0, stream>>>(Stc, ksc);
  chunk_out_kernel<<<dim3(BH*NCH), dim3(256), 0, stream>>>(qc, kc, vtc, Stc, ksc, attn);
  gemm_rms_kernel<<<dim3(M_/32), dim3(256), 0, stream>>>(attn, owb, b_out, gnorm, out);
}

// Round 2
// 155.999 us; speedup vs baseline: 1.1036x; 1.0306x over previous
//
#include <hip/hip_runtime.h>

typedef unsigned short u16;
typedef unsigned int u32;

#define B_ 2
#define L_ 4096
#define D_ 512
#define H_ 8
#define E_ 64
#define M_ (B_*L_)        // 8192 rows
#define TD (3*D_)         // 1536
#define NCH (L_/64)       // 64 chunks of 64 per sequence
#define BH (B_*H_)        // 16

typedef short bf16x8 __attribute__((ext_vector_type(8)));
typedef float f32x4 __attribute__((ext_vector_type(4)));

__device__ __forceinline__ float bf2f(u16 u){ return __uint_as_float(((u32)u)<<16); }
__device__ __forceinline__ u16 f2bf(float f){
  u32 u = __float_as_uint(f);
  u32 r = u + 0x7FFFu + ((u>>16)&1u);   // RNE; inputs finite
  return (u16)(r>>16);
}
__device__ __forceinline__ float elu1(float v){ return v>0.f ? v+1.f : __expf(v); }

__device__ __forceinline__ void async_ld16(const u16* g, u16* l){
  __builtin_amdgcn_global_load_lds(
      (const __attribute__((address_space(1))) void*)g,
      (__attribute__((address_space(3))) void*)l, 16, 0, 0);
}

// ---------------- K1: decay logits + x->bf16 + weight conversions ----------------
// blocks 0..2047: 4 rows each (decay logits + xb);  blocks 2048..3071: qw/ow -> bf16
// 8-head reduction via paired-halving transpose-reduce: 10 shuffles total (was 48).
__global__ __launch_bounds__(256) void decay_conv_kernel(const float* __restrict__ x,
    const float* __restrict__ dw, const float* __restrict__ db,
    const float* __restrict__ qw, const float* __restrict__ ow,
    float* __restrict__ ll, u16* __restrict__ xb,
    u16* __restrict__ qwb, u16* __restrict__ owb)
{
  int blk = blockIdx.x;
  if (blk < 2048){
    int wv = threadIdx.x>>6, lane = threadIdx.x&63;
    int m = blk*4 + wv;
    float xr[8];
    #pragma unroll
    for (int i=0;i<8;i++) xr[i] = x[(size_t)m*D_ + lane + 64*i];
    #pragma unroll
    for (int i=0;i<8;i++) xb[(size_t)m*D_ + lane + 64*i] = f2bf(xr[i]);
    int b = m >> 12, l = m & (L_-1);
    float acc8[8];
    #pragma unroll
    for (int h=0; h<8; h++){
      float a = 0.f;
      #pragma unroll
      for (int i=0;i<8;i++) a += xr[i]*dw[h*D_ + lane + 64*i];
      acc8[h] = a;
    }
    // step 1 (off=1): keep heads with bit0(h)==bit0(lane)
    float s4[4];
    #pragma unroll
    for (int i=0;i<4;i++){
      float a = acc8[2*i], bb = acc8[2*i+1];
      bool odd = lane & 1;
      float keep = odd ? bb : a;
      float send = odd ? a : bb;
      s4[i] = keep + __shfl_xor(send, 1);     // head = 2i + (lane&1)
    }
    // step 2 (off=2)
    float s2[2];
    #pragma unroll
    for (int j=0;j<2;j++){
      float a = s4[2*j], bb = s4[2*j+1];
      bool sel = (lane>>1) & 1;
      float keep = sel ? bb : a;
      float send = sel ? a : bb;
      s2[j] = keep + __shfl_xor(send, 2);     // head = 4j + (lane&3)
    }
    // step 3 (off=4)
    float r;
    {
      bool sel = (lane>>2) & 1;
      float keep = sel ? s2[1] : s2[0];
      float send = sel ? s2[0] : s2[1];
      r = keep + __shfl_xor(send, 4);         // head = lane&7, partial over lane-octet
    }
    r += __shfl_xor(r, 8);
    r += __shfl_xor(r, 16);
    r += __shfl_xor(r, 32);                    // full 64-lane sum for head lane&7
    if (lane < 8){
      float z = r + db[lane];
      float lam = 0.9f + 0.1f/(1.f + __expf(-z));
      ll[((b*H_+lane)*L_) + l] = __logf(lam);
    }
  } else {
    int gid = (blk-2048)*256 + threadIdx.x;   // 262144 float4 groups
    const float* src; u16* dst; int off;
    if (gid < 196608){ src = qw; dst = qwb; off = gid; }
    else { src = ow; dst = owb; off = gid - 196608; }
    float4 v = ((const float4*)src)[off];
    ushort4 o; o.x=f2bf(v.x); o.y=f2bf(v.y); o.z=f2bf(v.z); o.w=f2bf(v.w);
    ((ushort4*)dst)[off] = o;
  }
}

// ---------------- K2: inclusive scan over L (shfl-based), clip to [-50,50] ----------------
__global__ __launch_bounds__(256) void scan_kernel(const float* __restrict__ ll,
    float* __restrict__ cb)
{
  int bh = blockIdx.x, t = threadIdx.x;
  int lane = t & 63, wv = t >> 6;
  const float* p = ll + (size_t)bh*L_ + t*16;
  float s[16];
  #pragma unroll
  for (int q=0;q<4;q++){
    float4 v = *(const float4*)(p + q*4);
    s[q*4+0]=v.x; s[q*4+1]=v.y; s[q*4+2]=v.z; s[q*4+3]=v.w;
  }
  #pragma unroll
  for (int i=1;i<16;i++) s[i] += s[i-1];
  float tot = s[15];
  float ws = tot;
  #pragma unroll
  for (int off=1; off<64; off<<=1){
    float tmp = __shfl_up(ws, off);
    if (lane >= off) ws += tmp;
  }
  __shared__ float wsum[4];
  if (lane == 63) wsum[wv] = ws;
  __syncthreads();
  float base = 0.f;
  #pragma unroll
  for (int w2=0; w2<3; w2++) if (w2 < wv) base += wsum[w2];
  float ex = base + ws - tot;
  float* c = cb + (size_t)bh*L_ + t*16;
  #pragma unroll
  for (int i=0;i<16;i++) c[i] = fminf(50.f, fmaxf(-50.f, ex + s[i]));
}

// ---------------- MFMA GEMM: C[m][n] = sum_k A[m][k]*W[n][k] + bias[n] ----------------
// 2-phase double-buffered (T3 minimum): prefetch tile k+1 before computing tile k,
// one barrier per K-step -> staging latency hidden under ds_read+MFMA.
template<bool OB>
__global__ __launch_bounds__(256) void gemm_mfma(const u16* __restrict__ A,
    const u16* __restrict__ W, const float* __restrict__ bias,
    void* __restrict__ Cv, int M, int N, int K)
{
  __shared__ u16 As[2][128*32];
  __shared__ u16 Bs[2][128*32];
  int n0 = blockIdx.x*128, m0 = blockIdx.y*128;
  int t = threadIdx.x, wave = t>>6, lane = t&63;
  int wm = (wave>>1)*64, wn = (wave&1)*64;
  f32x4 acc[4][4] = {};
  int srow = wave*32 + (lane>>2);
  int scol = (lane&3)*8;
  const u16* gA = A + (size_t)(m0+srow)*K + scol;
  const u16* gB = W + (size_t)(n0+srow)*K + scol;
  int q8 = (lane>>4)*8, r16 = lane&15;
  // prologue: stage k0=0 into buf 0
  {
    u16* lA = As[0] + wave*1024;
    u16* lB = Bs[0] + wave*1024;
    async_ld16(gA,                lA);
    async_ld16(gA + 16*(size_t)K, lA + 512);
    async_ld16(gB,                lB);
    async_ld16(gB + 16*(size_t)K, lB + 512);
  }
  __syncthreads();
  int cur = 0;
  #pragma unroll 2
  for (int k0=0; k0<K; k0+=32){
    if (k0 + 32 < K){
      u16* lA = As[cur^1] + wave*1024;
      u16* lB = Bs[cur^1] + wave*1024;
      async_ld16(gA + k0+32,                lA);
      async_ld16(gA + k0+32 + 16*(size_t)K, lA + 512);
      async_ld16(gB + k0+32,                lB);
      async_ld16(gB + k0+32 + 16*(size_t)K, lB + 512);
    }
    bf16x8 af[4], bfr[4];
    #pragma unroll
    for (int i=0;i<4;i++) af[i]  = *(const bf16x8*)&As[cur][(wm + i*16 + r16)*32 + q8];
    #pragma unroll
    for (int j=0;j<4;j++) bfr[j] = *(const bf16x8*)&Bs[cur][(wn + j*16 + r16)*32 + q8];
    #pragma unroll
    for (int i=0;i<4;i++)
      #pragma unroll
      for (int j=0;j<4;j++)
        acc[i][j] = __builtin_amdgcn_mfma_f32_16x16x32_bf16(af[i], bfr[j], acc[i][j], 0,0,0);
    __syncthreads();
    cur ^= 1;
  }
  #pragma unroll
  for (int i=0;i<4;i++){
    int row = m0 + wm + i*16 + (lane>>4)*4;
    #pragma unroll
    for (int j=0;j<4;j++){
      int col = n0 + wn + j*16 + r16;
      float bv = bias[col];
      #pragma unroll
      for (int r=0;r<4;r++){
        float val = acc[i][j][r] + bv;
        if (OB) ((u16*)Cv)[(size_t)(row+r)*N + col] = f2bf(val);
        else    ((float*)Cv)[(size_t)(row+r)*N + col] = val;
      }
    }
  }
}

// ---------------- K4: fused transform + transpose + chunk S^T MFMA ----------------
// Ktl/Vtl padded to stride 40 u16 (80 B): ds_write conflicts 32-way -> 8-way.
// Ks/Vs padded to stride 72 u16 (144 B): keeps 16B-aligned uint4 stores.
__global__ __launch_bounds__(256) void transform_sums_kernel(const u16* __restrict__ qkvb,
    const float* __restrict__ cb, u16* __restrict__ qc, u16* __restrict__ kc,
    u16* __restrict__ vtc, u16* __restrict__ Stc, float* __restrict__ ksc)
{
  int bid = blockIdx.x;
  int bh = bid >> 6, ch = bid & 63;
  int b = bh >> 3, h = bh & 7;
  __shared__ u16 Ks[64*72];
  __shared__ u16 Vs[64*72];
  __shared__ u16 Ktl[128*40];
  __shared__ u16 Vtl[128*40];
  __shared__ float ksr[256];
  int t = threadIdx.x;
  size_t mbase = (size_t)b*L_ + ch*64;
  #pragma unroll
  for (int i=0;i<2;i++){
    int idx = t + 256*i;
    int l = idx>>3, e0 = (idx&7)*8;
    int kh = e0>>5, ej = e0&31;
    float c = cb[(size_t)bh*L_ + ch*64 + l];
    float eqc = __expf(c)*0.125f, ekc = __expf(-c);
    const u16* src = qkvb + (mbase+l)*TD + h*64 + e0;
    union { uint4 v; u16 s[8]; } in, o;
    // q
    in.v = *(const uint4*)src;
    #pragma unroll
    for (int j=0;j<8;j++) o.s[j] = f2bf(elu1(bf2f(in.s[j]))*eqc);
    *(uint4*)(qc + ((size_t)bid*2 + kh)*2048 + l*32 + ej) = o.v;
    // k
    in.v = *(const uint4*)(src + D_);
    #pragma unroll
    for (int j=0;j<8;j++) o.s[j] = f2bf(elu1(bf2f(in.s[j]))*ekc);
    *(uint4*)(kc + ((size_t)bid*2 + kh)*2048 + l*32 + ej) = o.v;
    *(uint4*)&Ks[l*72+e0] = o.v;
    // v
    *(uint4*)&Vs[l*72+e0] = *(const uint4*)(src + 2*D_);
  }
  __syncthreads();
  // transpose: thread (jq,e) -> K^T/V^T rows e, j in [jq*16, jq*16+16)
  int e = t & 63, jq = t >> 6;
  {
    u16 kv[16] __attribute__((aligned(16)));
    u16 vv[16] __attribute__((aligned(16)));
    float ksum = 0.f;
    #pragma unroll
    for (int jj=0;jj<16;jj++){
      int j = jq*16+jj;
      kv[jj] = Ks[j*72 + e];
      ksum += bf2f(kv[jj]);
      vv[jj] = Vs[j*72 + e];
    }
    int kh = jq>>1, jl = (jq&1)*16;
    u16* kt = &Ktl[(kh*64 + e)*40 + jl];
    u16* vt = &Vtl[(kh*64 + e)*40 + jl];
    *(uint4*)kt     = *(const uint4*)&kv[0];
    *(uint4*)(kt+8) = *(const uint4*)&kv[8];
    *(uint4*)vt     = *(const uint4*)&vv[0];
    *(uint4*)(vt+8) = *(const uint4*)&vv[8];
    ksr[t] = ksum;
  }
  __syncthreads();
  // Vtl -> global (chunked, unpadded stride-32 layout)
  {
    int row = t>>1, c0 = (t&1)*16;
    *(uint4*)&vtc[(size_t)bid*4096 + row*32 + c0]     = *(const uint4*)&Vtl[row*40 + c0];
    *(uint4*)&vtc[(size_t)bid*4096 + row*32 + c0 + 8] = *(const uint4*)&Vtl[row*40 + c0 + 8];
  }
  // MFMA: St[f][e] = sum_j Vt[f][j] Kt[e][j]
  int w = t>>6, lane = t&63;
  int r16 = lane & 15, q8 = (lane>>4)*8;
  bf16x8 av[2];
  #pragma unroll
  for (int kh=0;kh<2;kh++)
    av[kh] = *(const bf16x8*)&Vtl[(kh*64 + w*16 + r16)*40 + q8];
  f32x4 acc[4] = {};
  #pragma unroll
  for (int et=0;et<4;et++)
    #pragma unroll
    for (int kh=0;kh<2;kh++){
      bf16x8 bv = *(const bf16x8*)&Ktl[(kh*64 + et*16 + r16)*40 + q8];
      acc[et] = __builtin_amdgcn_mfma_f32_16x16x32_bf16(av[kh], bv, acc[et], 0,0,0);
    }
  #pragma unroll
  for (int et=0;et<4;et++){
    int eh = et>>1, el = (et&1)*16 + r16;
    #pragma unroll
    for (int r=0;r<4;r++){
      int f = w*16 + (lane>>4)*4 + r;
      Stc[((size_t)bid*2 + eh)*2048 + f*32 + el] = f2bf(acc[et][r]);
    }
  }
  if (t < 64) ksc[bid*64 + t] = ksr[t] + ksr[64+t] + ksr[128+t] + ksr[192+t];
}

// ---------------- K5: exclusive prefix over chunks ----------------
// blocks 0..127: Stc scan (u32-packed bf16 pairs), unroll 16 (16 loads in flight)
// blocks 128..131: ksc scan in parallel
__global__ __launch_bounds__(256) void chunk_prefix_kernel(u16* __restrict__ Stc,
    float* __restrict__ ksc)
{
  int blk = blockIdx.x, t = threadIdx.x;
  if (blk < 128){
    int gid = blk*256 + t;                 // 32768 threads
    int bh = gid >> 11, e2 = gid & 2047;
    u32* p = (u32*)Stc + (size_t)bh*131072 + e2;
    float r0 = 0.f, r1 = 0.f;
    #pragma unroll 16
    for (int ch=0; ch<NCH; ch++){
      u32 v = p[ch*2048];
      float lo = bf2f((u16)(v & 0xffffu));
      float hi = bf2f((u16)(v >> 16));
      p[ch*2048] = (u32)f2bf(r0) | ((u32)f2bf(r1) << 16);
      r0 += lo; r1 += hi;
    }
  } else {
    int gid2 = (blk-128)*256 + t;          // 1024 threads = BH*64
    int bh2 = gid2 >> 6, e = gid2 & 63;
    float* kp = ksc + bh2*4096 + e;
    float kr = 0.f;
    #pragma unroll 8
    for (int ch=0; ch<NCH; ch++){
      float v = kp[ch*64]; kp[ch*64] = kr; kr += v;
    }
  }
}

// ---------------- K6: chunk output via MFMA (async chunked staging) ----------------
__global__ __launch_bounds__(256) void chunk_out_kernel(const u16* __restrict__ qc,
    const u16* __restrict__ kc, const u16* __restrict__ vtc,
    const u16* __restrict__ Stc, const float* __restrict__ ksc,
    u16* __restrict__ attn)
{
  int bid = blockIdx.x;
  int bh = bid >> 6, ch = bid & 63;
  int b = bh >> 3, h = bh & 7;
  __shared__ u16 KV[16384];     // Qs | Kb_s | Vt_s | St_s, each [half][row][32]
  __shared__ u16 Ab[4096];      // [jh][l][32]
  __shared__ float kp[64], den4[256], den[64];
  int t = threadIdx.x, w = t>>6, lane = t&63;
  size_t mbase = (size_t)b*L_ + ch*64;
  // wave-uniform select (no runtime-indexed pointer array -> no scratch)
  const u16* gsrc = (w==0) ? qc : (w==1) ? kc : (w==2) ? vtc : Stc;
  {
    const u16* gbase = gsrc + (size_t)bid*4096 + lane*8;
    #pragma unroll
    for (int q=0;q<8;q++)
      async_ld16(gbase + q*512, KV + w*4096 + q*512);
  }
  if (t < 64) kp[t] = ksc[bid*64 + t];
  __syncthreads();   // B1
  const u16* Qs   = KV;
  const u16* Kb_s = KV + 4096;
  const u16* Vt_s = KV + 8192;
  const u16* St_s = KV + 12288;
  int r16 = lane & 15, q8 = (lane>>4)*8;
  // matmul1: A = Q~ K~^T  (strip l = w*16..w*16+15)
  bf16x8 aq[2];
  #pragma unroll
  for (int eh=0;eh<2;eh++)
    aq[eh] = *(const bf16x8*)&Qs[(eh*64 + w*16 + r16)*32 + q8];
  f32x4 accA[4] = {};
  #pragma unroll
  for (int jt=0;jt<4;jt++)
    #pragma unroll
    for (int eh=0;eh<2;eh++){
      bf16x8 bv = *(const bf16x8*)&Kb_s[(eh*64 + jt*16 + r16)*32 + q8];
      accA[jt] = __builtin_amdgcn_mfma_f32_16x16x32_bf16(aq[eh], bv, accA[jt], 0,0,0);
    }
  // den: q~ . kp part
  int l4 = t>>2, q4 = t&3;
  float dkp = 0.f;
  {
    int eh = q4>>1, el0 = (q4&1)*16;
    bf16x8 x1 = *(const bf16x8*)&Qs[(eh*64 + l4)*32 + el0];
    bf16x8 x2 = *(const bf16x8*)&Qs[(eh*64 + l4)*32 + el0 + 8];
    #pragma unroll
    for (int i=0;i<8;i++)
      dkp += bf2f((u16)x1[i])*kp[q4*16+i] + bf2f((u16)x2[i])*kp[q4*16+8+i];
  }
  // mask + write A to LDS (bf16, split layout)
  #pragma unroll
  for (int jt=0;jt<4;jt++)
    #pragma unroll
    for (int r=0;r<4;r++){
      int lr = w*16 + ((lane>>4)<<2) + r;
      int j  = jt*16 + r16;
      Ab[((jt>>1)*64 + lr)*32 + (jt&1)*16 + r16] = (j <= lr) ? f2bf(accA[jt][r]) : (u16)0;
    }
  __syncthreads();   // B2
  // den: masked row-sum of A
  float dA = 0.f;
  {
    int jh2 = q4>>1, jl0 = (q4&1)*16;
    bf16x8 y1 = *(const bf16x8*)&Ab[(jh2*64 + l4)*32 + jl0];
    bf16x8 y2 = *(const bf16x8*)&Ab[(jh2*64 + l4)*32 + jl0 + 8];
    #pragma unroll
    for (int i=0;i<8;i++) dA += bf2f((u16)y1[i]) + bf2f((u16)y2[i]);
  }
  den4[t] = dkp + dA;
  __syncthreads();   // B3
  if (t < 64) den[t] = den4[t*4] + den4[t*4+1] + den4[t*4+2] + den4[t*4+3] + 1e-6f;
  // matmul2: num = A V + Q~ S^T
  bf16x8 aA[2];
  #pragma unroll
  for (int jh=0;jh<2;jh++)
    aA[jh] = *(const bf16x8*)&Ab[(jh*64 + w*16 + r16)*32 + q8];
  f32x4 acc[4] = {};
  #pragma unroll
  for (int ft=0;ft<4;ft++){
    #pragma unroll
    for (int jh=0;jh<2;jh++){
      bf16x8 bv = *(const bf16x8*)&Vt_s[(jh*64 + ft*16 + r16)*32 + q8];
      acc[ft] = __builtin_amdgcn_mfma_f32_16x16x32_bf16(aA[jh], bv, acc[ft], 0,0,0);
    }
    #pragma unroll
    for (int eh=0;eh<2;eh++){
      bf16x8 bv = *(const bf16x8*)&St_s[(eh*64 + ft*16 + r16)*32 + q8];
      acc[ft] = __builtin_amdgcn_mfma_f32_16x16x32_bf16(aq[eh], bv, acc[ft], 0,0,0);
    }
  }
  __syncthreads();   // B4
  float inv[4];
  #pragma unroll
  for (int r=0;r<4;r++) inv[r] = 1.f / den[w*16 + ((lane>>4)<<2) + r];
  #pragma unroll
  for (int ft=0;ft<4;ft++)
    #pragma unroll
    for (int r=0;r<4;r++){
      int lr = w*16 + ((lane>>4)<<2) + r;
      attn[(mbase + lr)*D_ + h*64 + ft*16 + r16] = f2bf(acc[ft][r]*inv[r]);
    }
}

// ---------------- K7: out-projection GEMM fused with RMSNorm epilogue ----------------
// BM=32, BN=512 (full row band per block); 2-phase double-buffered staging.
__global__ __launch_bounds__(256) void gemm_rms_kernel(const u16* __restrict__ A,
    const u16* __restrict__ W, const float* __restrict__ bias,
    const float* __restrict__ gnorm, float* __restrict__ out)
{
  __shared__ u16 As[2][32*32];
  __shared__ u16 Bs[2][512*32];
  __shared__ float ssq_l[4][32];
  __shared__ float rinv_l[32];
  int m0 = blockIdx.x*32;
  int t = threadIdx.x, wave = t>>6, lane = t&63;
  int wn = wave*128;
  int r16 = lane&15, q8 = (lane>>4)*8;
  f32x4 acc[2][8] = {};
  int scol = (t&3)*8;
  const u16* gB = W + (size_t)(t>>2)*512 + scol;               // rows (t>>2) + it*64
  const u16* gA = A + (size_t)(m0 + (t>>2))*512 + scol;        // valid for waves 0,1
  // prologue: stage k0=0 into buf 0
  {
    if (wave < 2) async_ld16(gA, As[0] + wave*512);
    #pragma unroll
    for (int it=0; it<8; it++)
      async_ld16(gB + it*32768, Bs[0] + wave*512 + it*2048);
  }
  __syncthreads();
  int cur = 0;
  #pragma unroll 2
  for (int k0=0; k0<512; k0+=32){
    if (k0 < 480){
      if (wave < 2) async_ld16(gA + k0+32, As[cur^1] + wave*512);
      #pragma unroll
      for (int it=0; it<8; it++)
        async_ld16(gB + k0+32 + it*32768, Bs[cur^1] + wave*512 + it*2048);
    }
    bf16x8 af0 = *(const bf16x8*)&As[cur][r16*32 + q8];
    bf16x8 af1 = *(const bf16x8*)&As[cur][(16 + r16)*32 + q8];
    #pragma unroll
    for (int j=0;j<8;j++){
      bf16x8 bv = *(const bf16x8*)&Bs[cur][(wn + j*16 + r16)*32 + q8];
      acc[0][j] = __builtin_amdgcn_mfma_f32_16x16x32_bf16(af0, bv, acc[0][j], 0,0,0);
      acc[1][j] = __builtin_amdgcn_mfma_f32_16x16x32_bf16(af1, bv, acc[1][j], 0,0,0);
    }
    __syncthreads();
    cur ^= 1;
  }
  // epilogue: bias, row sum-of-squares (across 4 waves), rsqrt, scale, fp32 store
  int g = lane>>4;
  float bv8[8], gv8[8];
  #pragma unroll
  for (int j=0;j<8;j++){ int col = wn + j*16 + r16; bv8[j] = bias[col]; gv8[j] = gnorm[col]; }
  float ssq[2][4] = {};
  #pragma unroll
  for (int i=0;i<2;i++)
    #pragma unroll
    for (int j=0;j<8;j++)
      #pragma unroll
      for (int r=0;r<4;r++){
        float v = acc[i][j][r] + bv8[j];
        acc[i][j][r] = v;
        ssq[i][r] += v*v;
      }
  #pragma unroll
  for (int off=1; off<16; off<<=1)
    #pragma unroll
    for (int i=0;i<2;i++)
      #pragma unroll
      for (int r=0;r<4;r++)
        ssq[i][r] += __shfl_xor(ssq[i][r], off);
  if (r16 == 0){
    #pragma unroll
    for (int i=0;i<2;i++)
      #pragma unroll
      for (int r=0;r<4;r++)
        ssq_l[wave][i*16 + g*4 + r] = ssq[i][r];
  }
  __syncthreads();
  if (t < 32)
    rinv_l[t] = rsqrtf((ssq_l[0][t]+ssq_l[1][t]+ssq_l[2][t]+ssq_l[3][t])*(1.f/512.f) + 1e-8f);
  __syncthreads();
  #pragma unroll
  for (int i=0;i<2;i++)
    #pragma unroll
    for (int r=0;r<4;r++){
      int row = m0 + i*16 + g*4 + r;
      float ri = rinv_l[i*16 + g*4 + r];
      #pragma unroll
      for (int j=0;j<8;j++)
        out[(size_t)row*512 + wn + j*16 + r16] = acc[i][j][r]*ri*gv8[j];
    }
}

extern "C" void kernel_launch(void* const* d_in, const int* in_sizes, int n_in,
                              void* d_out, int out_size, void* d_ws, size_t ws_size,
                              hipStream_t stream)
{
  const float* x     = (const float*)d_in[0];
  const float* w_qkv = (const float*)d_in[1];
  const float* b_qkv = (const float*)d_in[2];
  const float* w_out = (const float*)d_in[3];
  const float* b_out = (const float*)d_in[4];
  const float* w_dec = (const float*)d_in[5];
  const float* b_dec = (const float*)d_in[6];
  const float* gnorm = (const float*)d_in[7];
  float* out = (float*)d_out;

  char* ws = (char*)d_ws;
  u16*   qkvb = (u16*)(ws);                    // 25,165,824  [M][1536] bf16
  u16*   qc   = (u16*)(ws + 25165824);         //  8,388,608  chunked [bid][eh][l][32]
  u16*   kc   = (u16*)(ws + 33554432);         //  8,388,608  chunked [bid][eh][j][32]
  u16*   vtc  = (u16*)(ws + 41943040);         //  8,388,608  chunked [bid][jh][f][32]
  u16*   Stc  = (u16*)(ws + 50331648);         //  8,388,608  chunked [bid][eh][f][32]
  float* ksc  = (float*)(ws + 58720256);       //    262,144
  float* ll   = (float*)(ws + 58982400);       //    262,144
  float* cb   = (float*)(ws + 59244544);       //    262,144
  u16*   xb   = (u16*)(ws + 59506688);         //  8,388,608  (attn reuses after gemm_qkv)
  u16*   qwb  = (u16*)(ws + 67895296);         //  1,572,864
  u16*   owb  = (u16*)(ws + 69468160);         //    524,288  total 69,992,448
  u16*   attn = xb;

  decay_conv_kernel<<<dim3(3072), dim3(256), 0, stream>>>(x, w_dec, b_dec, w_qkv, w_out,
                                                          ll, xb, qwb, owb);
  scan_kernel<<<dim3(BH), dim3(256), 0, stream>>>(ll, cb);
  gemm_mfma<true><<<dim3(TD/128, M_/128), dim3(256), 0, stream>>>(xb, qwb, b_qkv, qkvb, M_, TD, D_);
  transform_sums_kernel<<<dim3(BH*NCH), dim3(256), 0, stream>>>(qkvb, cb, qc, kc, vtc, Stc, ksc);
  chunk_prefix_kernel<<<dim3(132), dim3(256), 0, stream>>>(Stc, ksc);
  chunk_out_kernel<<<dim3(BH*NCH), dim3(256), 0, stream>>>(qc, kc, vtc, Stc, ksc, attn);
  gemm_rms_kernel<<<dim3(M_/32), dim3(256), 0, stream>>>(attn, owb, b_out, gnorm, out);
}